// Round 1
// baseline (1333.775 us; speedup 1.0000x reference)
//
#include <hip/hip_runtime.h>

// N=100000 nodes, E=1000000 edges, D_IN=16, H=2, C=64.
// 3x (GAT -> BN -> ReLU), then MLP head -> (logits, value) concat in d_out.

__device__ __forceinline__ float leaky(float x) { return x > 0.f ? x : 0.2f * x; }

// ---------------- CSR build (dst-sorted; self-loops implicit) ----------------
__global__ void hist_kernel(const int* __restrict__ dst, int* __restrict__ deg, int E) {
  int e = blockIdx.x * blockDim.x + threadIdx.x;
  if (e < E) atomicAdd(&deg[dst[e]], 1);
}

// single-block exclusive scan over n entries (n ~ 100k): 1024 threads, chunked
__global__ void scan_kernel(const int* __restrict__ deg, int* __restrict__ row_ptr, int n) {
  __shared__ int temp[1024];
  __shared__ int running_s;
  if (threadIdx.x == 0) running_s = 0;
  __syncthreads();
  for (int base = 0; base < n; base += 1024) {
    int i = base + threadIdx.x;
    int v = (i < n) ? deg[i] : 0;
    temp[threadIdx.x] = v;
    __syncthreads();
    for (int off = 1; off < 1024; off <<= 1) {
      int add = (threadIdx.x >= off) ? temp[threadIdx.x - off] : 0;
      __syncthreads();
      temp[threadIdx.x] += add;
      __syncthreads();
    }
    int excl = temp[threadIdx.x] - v;
    if (i < n) row_ptr[i] = running_s + excl;
    int total = temp[1023];
    __syncthreads();
    if (threadIdx.x == 0) running_s += total;
    __syncthreads();
  }
  if (threadIdx.x == 0) row_ptr[n] = running_s;
}

__global__ void copy_kernel(const int* __restrict__ a, int* __restrict__ b, int n) {
  int i = blockIdx.x * blockDim.x + threadIdx.x;
  if (i < n) b[i] = a[i];
}

__global__ void scatter_kernel(const int* __restrict__ src, const int* __restrict__ dst,
                               int* __restrict__ cursor, int* __restrict__ col, int E) {
  int e = blockIdx.x * blockDim.x + threadIdx.x;
  if (e < E) {
    int d = dst[e];
    int pos = atomicAdd(&cursor[d], 1);
    col[pos] = src[e];
  }
}

// ---------------- GAT projection: h = act @ W (K x 128), + a_s/a_d ----------
// grid = N blocks, 128 threads (wave 0 = head 0 cols 0..63, wave 1 = head 1)
__global__ void gat_project(const float* __restrict__ act, const float* __restrict__ W,
                            const float* __restrict__ att_s, const float* __restrict__ att_d,
                            float* __restrict__ hbuf, float* __restrict__ as_,
                            float* __restrict__ ad_, int K) {
  int n = blockIdx.x;
  int t = threadIdx.x;            // 0..127
  int head = t >> 6, lane = t & 63;
  const float* arow = act + (size_t)n * K;
  float sum = 0.f;
#pragma unroll 8
  for (int k = 0; k < K; k++) sum = fmaf(arow[k], W[k * 128 + t], sum);
  hbuf[(size_t)n * 128 + t] = sum;
  float ps = sum * att_s[t];      // att layout (H,C) flat == t
  float pd = sum * att_d[t];
  for (int off = 32; off; off >>= 1) {
    ps += __shfl_down(ps, off);
    pd += __shfl_down(pd, off);
  }
  if (lane == 0) { as_[n * 2 + head] = ps; ad_[n * 2 + head] = pd; }
}

// ---------------- GAT aggregation: one wave per dst node ---------------------
__global__ __launch_bounds__(256) void gat_aggregate(
    const float* __restrict__ hbuf, const float* __restrict__ as_,
    const float* __restrict__ ad_, const int* __restrict__ row_ptr,
    const int* __restrict__ col, const float* __restrict__ bias,
    float* __restrict__ out, int n) {
  int wave = (int)((blockIdx.x * blockDim.x + threadIdx.x) >> 6);
  int lane = threadIdx.x & 63;
  if (wave >= n) return;
  int d = wave;
  int beg = row_ptr[d], end = row_ptr[d + 1];
  float ad0 = ad_[d * 2 + 0], ad1 = ad_[d * 2 + 1];
  // self-loop score (always present)
  float e0s = leaky(as_[d * 2 + 0] + ad0);
  float e1s = leaky(as_[d * 2 + 1] + ad1);
  float m0 = e0s, m1 = e1s;
  // pass 1: segment max, lanes parallel over edges
  for (int k = beg + lane; k < end; k += 64) {
    int s = col[k];
    m0 = fmaxf(m0, leaky(as_[s * 2 + 0] + ad0));
    m1 = fmaxf(m1, leaky(as_[s * 2 + 1] + ad1));
  }
  for (int off = 32; off; off >>= 1) {
    m0 = fmaxf(m0, __shfl_down(m0, off));
    m1 = fmaxf(m1, __shfl_down(m1, off));
  }
  m0 = __shfl(m0, 0);
  m1 = __shfl(m1, 0);
  // pass 2: accumulate sum(ee) and sum(ee * h[src]); normalize once at end
  float acc0, acc1, den0, den1;
  {
    float ee0 = __expf(e0s - m0), ee1 = __expf(e1s - m1);
    den0 = ee0; den1 = ee1;
    acc0 = ee0 * hbuf[(size_t)d * 128 + lane];
    acc1 = ee1 * hbuf[(size_t)d * 128 + 64 + lane];
  }
  for (int k = beg; k < end; ++k) {
    int s = col[k];  // wave-uniform broadcast load
    float e0 = leaky(as_[s * 2 + 0] + ad0);
    float e1 = leaky(as_[s * 2 + 1] + ad1);
    float ee0 = __expf(e0 - m0), ee1 = __expf(e1 - m1);
    den0 += ee0; den1 += ee1;
    acc0 = fmaf(ee0, hbuf[(size_t)s * 128 + lane], acc0);
    acc1 = fmaf(ee1, hbuf[(size_t)s * 128 + 64 + lane], acc1);
  }
  float o = 0.5f * (acc0 / (den0 + 1e-16f) + acc1 / (den1 + 1e-16f)) + bias[lane];
  out[(size_t)d * 64 + lane] = o;
}

// ---------------- BatchNorm ----------------
__global__ void bn_stats(const float* __restrict__ h, float* __restrict__ stats, int n) {
  __shared__ float ssum[64], ssq[64];
  int t = threadIdx.x;
  if (t < 64) { ssum[t] = 0.f; ssq[t] = 0.f; }
  __syncthreads();
  int c = t & 63;  // stride and start are multiples of 64 -> channel constant
  float lsum = 0.f, lsq = 0.f;
  size_t total = (size_t)n * 64;
  for (size_t i = (size_t)blockIdx.x * blockDim.x + t; i < total;
       i += (size_t)gridDim.x * blockDim.x) {
    float v = h[i];
    lsum += v;
    lsq = fmaf(v, v, lsq);
  }
  atomicAdd(&ssum[c], lsum);
  atomicAdd(&ssq[c], lsq);
  __syncthreads();
  if (t < 64) {
    atomicAdd(&stats[t], ssum[t]);
    atomicAdd(&stats[64 + t], ssq[t]);
  }
}

__global__ void bn_apply(const float* __restrict__ hin, const float* __restrict__ stats,
                         const float* __restrict__ g, const float* __restrict__ be,
                         float* __restrict__ out, int n) {
  size_t i = (size_t)blockIdx.x * blockDim.x + threadIdx.x;
  if (i >= (size_t)n * 64) return;
  int c = (int)(i & 63);
  float inv_n = 1.0f / (float)n;
  float mean = stats[c] * inv_n;
  float var = stats[64 + c] * inv_n - mean * mean;
  float sc = rsqrtf(var + 1e-5f) * g[c];
  float v = (hin[i] - mean) * sc + be[c];
  out[i] = v > 0.f ? v : 0.f;
}

// ---------------- MLP head: one wave per node ----------------
__global__ __launch_bounds__(256) void mlp_head(
    const float* __restrict__ h3, const float* __restrict__ x,
    const float* __restrict__ mW1, const float* __restrict__ mb1,
    const float* __restrict__ mW2, const float* __restrict__ mb2,
    const float* __restrict__ pW, const float* __restrict__ pb,
    const float* __restrict__ vW, const float* __restrict__ vb,
    float* __restrict__ out, int n) {
  int wave = (int)((blockIdx.x * blockDim.x + threadIdx.x) >> 6);
  int lane = threadIdx.x & 63;
  if (wave >= n) return;
  float hval = h3[(size_t)wave * 64 + lane];
  float t1 = mb1[lane];
#pragma unroll 8
  for (int k = 0; k < 64; k++) {
    float a = __shfl(hval, k);
    t1 = fmaf(a, mW1[k * 64 + lane], t1);
  }
  const float* xrow = x + (size_t)wave * 16;
#pragma unroll
  for (int j = 0; j < 5; j++) t1 = fmaf(xrow[9 + j], mW1[(64 + j) * 64 + lane], t1);
  t1 = fmaxf(t1, 0.f);
  float u = mb2[lane];
#pragma unroll 8
  for (int k = 0; k < 64; k++) {
    float a = __shfl(t1, k);
    u = fmaf(a, mW2[k * 64 + lane], u);
  }
  float pl = u * pW[lane];
  float vl = u * vW[lane];
  for (int off = 32; off; off >>= 1) {
    pl += __shfl_down(pl, off);
    vl += __shfl_down(vl, off);
  }
  if (lane == 0) {
    out[wave] = pl + pb[0];
    out[n + wave] = vl + vb[0];
  }
}

extern "C" void kernel_launch(void* const* d_in, const int* in_sizes, int n_in,
                              void* d_out, int out_size, void* d_ws, size_t ws_size,
                              hipStream_t stream) {
  const float* x = (const float*)d_in[0];
  const int* ei = (const int*)d_in[1];
  const float* W[3]  = {(const float*)d_in[2],  (const float*)d_in[8],  (const float*)d_in[14]};
  const float* AS[3] = {(const float*)d_in[3],  (const float*)d_in[9],  (const float*)d_in[15]};
  const float* AD[3] = {(const float*)d_in[4],  (const float*)d_in[10], (const float*)d_in[16]};
  const float* B[3]  = {(const float*)d_in[5],  (const float*)d_in[11], (const float*)d_in[17]};
  const float* G[3]  = {(const float*)d_in[6],  (const float*)d_in[12], (const float*)d_in[18]};
  const float* BE[3] = {(const float*)d_in[7],  (const float*)d_in[13], (const float*)d_in[19]};
  const float* mW1 = (const float*)d_in[20];
  const float* mb1 = (const float*)d_in[21];
  const float* mW2 = (const float*)d_in[22];
  const float* mb2 = (const float*)d_in[23];
  const float* pW  = (const float*)d_in[24];
  const float* pb  = (const float*)d_in[25];
  const float* vW  = (const float*)d_in[26];
  const float* vb  = (const float*)d_in[27];

  const int N = in_sizes[0] / 16;
  const int E = in_sizes[1] / 2;
  const int* srcp = ei;
  const int* dstp = ei + E;

  // workspace carve-up (~109 MB)
  float* bufA  = (float*)d_ws;               // N*64  activations (layer in/out)
  float* bufB  = bufA + (size_t)N * 64;      // N*64  pre-BN aggregation output
  float* hbuf  = bufB + (size_t)N * 64;      // N*128 projected features
  float* as_   = hbuf + (size_t)N * 128;     // N*2
  float* ad_   = as_ + (size_t)N * 2;        // N*2
  float* stats = ad_ + (size_t)N * 2;        // 128
  int* row_ptr = (int*)(stats + 128);        // N+1
  int* cursor  = row_ptr + (N + 1);          // N
  int* colbuf  = cursor + N;                 // E

  // ---- CSR build (graph is identical each call; rebuilt since inputs are re-poisoned)
  hipMemsetAsync(cursor, 0, sizeof(int) * (size_t)N, stream);
  hist_kernel<<<(E + 255) / 256, 256, 0, stream>>>(dstp, cursor, E);
  scan_kernel<<<1, 1024, 0, stream>>>(cursor, row_ptr, N);
  copy_kernel<<<(N + 255) / 256, 256, 0, stream>>>(row_ptr, cursor, N);
  scatter_kernel<<<(E + 255) / 256, 256, 0, stream>>>(srcp, dstp, cursor, colbuf, E);

  // ---- 3 GAT layers
  const float* in = x;
  int K = 16;
  for (int l = 0; l < 3; l++) {
    gat_project<<<N, 128, 0, stream>>>(in, W[l], AS[l], AD[l], hbuf, as_, ad_, K);
    gat_aggregate<<<(N + 3) / 4, 256, 0, stream>>>(hbuf, as_, ad_, row_ptr, colbuf, B[l], bufB, N);
    hipMemsetAsync(stats, 0, sizeof(float) * 128, stream);
    bn_stats<<<1024, 256, 0, stream>>>(bufB, stats, N);
    bn_apply<<<(N * 64 + 255) / 256, 256, 0, stream>>>(bufB, stats, G[l], BE[l], bufA, N);
    in = bufA;
    K = 64;
  }

  // ---- MLP head -> (logits, value)
  mlp_head<<<(N + 3) / 4, 256, 0, stream>>>(bufA, x, mW1, mb1, mW2, mb2,
                                            pW, pb, vW, vb, (float*)d_out, N);
}

// Round 2
// 1032.293 us; speedup vs baseline: 1.2921x; 1.2921x over previous
//
#include <hip/hip_runtime.h>

// N=100000 nodes, E=1000000 edges, D_IN=16, H=2, C=64.
// 3x (GAT -> BN -> ReLU), then MLP head -> (logits, value) concat in d_out.

__device__ __forceinline__ float leaky(float x) { return x > 0.f ? x : 0.2f * x; }

// ---------------- CSR build (dst-sorted; self-loops implicit) ----------------
__global__ void hist_kernel(const int* __restrict__ dst, int* __restrict__ deg, int E) {
  int e = blockIdx.x * blockDim.x + threadIdx.x;
  if (e < E) atomicAdd(&deg[dst[e]], 1);
}

// ---- multi-block exclusive scan: phase 1 (per-block partial sums) ----
// block b covers items [b*512, b*512+512), 256 threads x 2 items
__global__ void scan_phase1(const int* __restrict__ deg, int* __restrict__ bsum, int n) {
  __shared__ int red[256];
  int t = threadIdx.x;
  int i0 = blockIdx.x * 512 + t * 2;
  int d0 = (i0 < n) ? deg[i0] : 0;
  int d1 = (i0 + 1 < n) ? deg[i0 + 1] : 0;
  red[t] = d0 + d1;
  __syncthreads();
  for (int off = 128; off; off >>= 1) {
    if (t < off) red[t] += red[t + off];
    __syncthreads();
  }
  if (t == 0) bsum[blockIdx.x] = red[0];
}

// ---- phase 2: single-block exclusive scan of nb (<=256) block sums ----
__global__ void scan_phase2(const int* __restrict__ bsum, int* __restrict__ boff,
                            int* __restrict__ row_ptr_last, int nb) {
  __shared__ int temp[256];
  int t = threadIdx.x;
  int v = (t < nb) ? bsum[t] : 0;
  temp[t] = v;
  __syncthreads();
  for (int off = 1; off < 256; off <<= 1) {
    int add = (t >= off) ? temp[t - off] : 0;
    __syncthreads();
    temp[t] += add;
    __syncthreads();
  }
  if (t < nb) boff[t] = temp[t] - v;           // exclusive
  if (t == nb - 1) *row_ptr_last = temp[t];    // grand total -> row_ptr[N]
}

// ---- phase 3: per-block exclusive scan + offset, emit row_ptr ----
__global__ void scan_phase3(const int* __restrict__ deg, const int* __restrict__ boff,
                            int* __restrict__ row_ptr, int n) {
  __shared__ int temp[256];
  int t = threadIdx.x;
  int i0 = blockIdx.x * 512 + t * 2;
  int d0 = (i0 < n) ? deg[i0] : 0;
  int d1 = (i0 + 1 < n) ? deg[i0 + 1] : 0;
  int pair = d0 + d1;
  temp[t] = pair;
  __syncthreads();
  for (int off = 1; off < 256; off <<= 1) {
    int add = (t >= off) ? temp[t - off] : 0;
    __syncthreads();
    temp[t] += add;
    __syncthreads();
  }
  int excl = boff[blockIdx.x] + temp[t] - pair;
  if (i0 < n) row_ptr[i0] = excl;
  if (i0 + 1 < n) row_ptr[i0 + 1] = excl + d0;
}

__global__ void copy_kernel(const int* __restrict__ a, int* __restrict__ b, int n) {
  int i = blockIdx.x * blockDim.x + threadIdx.x;
  if (i < n) b[i] = a[i];
}

__global__ void scatter_kernel(const int* __restrict__ src, const int* __restrict__ dst,
                               int* __restrict__ cursor, int* __restrict__ col, int E) {
  int e = blockIdx.x * blockDim.x + threadIdx.x;
  if (e < E) {
    int d = dst[e];
    int pos = atomicAdd(&cursor[d], 1);
    col[pos] = src[e];
  }
}

// ---------------- GAT projection: h = act @ W (K x 128), + a_s/a_d ----------
// grid = N blocks, 128 threads (wave 0 = head 0 cols 0..63, wave 1 = head 1)
__global__ void gat_project(const float* __restrict__ act, const float* __restrict__ W,
                            const float* __restrict__ att_s, const float* __restrict__ att_d,
                            float* __restrict__ hbuf, float* __restrict__ as_,
                            float* __restrict__ ad_, int K) {
  int n = blockIdx.x;
  int t = threadIdx.x;            // 0..127
  int head = t >> 6, lane = t & 63;
  const float* arow = act + (size_t)n * K;
  float sum = 0.f;
#pragma unroll 8
  for (int k = 0; k < K; k++) sum = fmaf(arow[k], W[k * 128 + t], sum);
  hbuf[(size_t)n * 128 + t] = sum;
  float ps = sum * att_s[t];      // att layout (H,C) flat == t
  float pd = sum * att_d[t];
  for (int off = 32; off; off >>= 1) {
    ps += __shfl_down(ps, off);
    pd += __shfl_down(pd, off);
  }
  if (lane == 0) { as_[n * 2 + head] = ps; ad_[n * 2 + head] = pd; }
}

// ---------------- GAT aggregation: one wave per dst node ---------------------
// Softmax max-shift dropped (normalization-invariant; scores are O(1)).
__global__ __launch_bounds__(256) void gat_aggregate(
    const float* __restrict__ hbuf, const float* __restrict__ as_,
    const float* __restrict__ ad_, const int* __restrict__ row_ptr,
    const int* __restrict__ col, const float* __restrict__ bias,
    float* __restrict__ out, int n) {
  int wave = (int)((blockIdx.x * blockDim.x + threadIdx.x) >> 6);
  int lane = threadIdx.x & 63;
  if (wave >= n) return;
  int d = wave;
  int beg = row_ptr[d], end = row_ptr[d + 1];
  float ad0 = ad_[d * 2 + 0], ad1 = ad_[d * 2 + 1];
  // self-loop contribution (always present)
  float acc0a, acc1a, den0a, den1a;
  {
    float ee0 = __expf(leaky(as_[d * 2 + 0] + ad0));
    float ee1 = __expf(leaky(as_[d * 2 + 1] + ad1));
    den0a = ee0; den1a = ee1;
    acc0a = ee0 * hbuf[(size_t)d * 128 + lane];
    acc1a = ee1 * hbuf[(size_t)d * 128 + 64 + lane];
  }
  float acc0b = 0.f, acc1b = 0.f, den0b = 0.f, den1b = 0.f;
  int k = beg;
  // 2-way unrolled edge walk: independent chains for load/FMA ILP
  for (; k + 1 < end; k += 2) {
    int sA = col[k], sB = col[k + 1];
    float eA0 = leaky(as_[sA * 2 + 0] + ad0);
    float eA1 = leaky(as_[sA * 2 + 1] + ad1);
    float eB0 = leaky(as_[sB * 2 + 0] + ad0);
    float eB1 = leaky(as_[sB * 2 + 1] + ad1);
    float hA0 = hbuf[(size_t)sA * 128 + lane];
    float hA1 = hbuf[(size_t)sA * 128 + 64 + lane];
    float hB0 = hbuf[(size_t)sB * 128 + lane];
    float hB1 = hbuf[(size_t)sB * 128 + 64 + lane];
    float eeA0 = __expf(eA0), eeA1 = __expf(eA1);
    float eeB0 = __expf(eB0), eeB1 = __expf(eB1);
    den0a += eeA0; den1a += eeA1;
    den0b += eeB0; den1b += eeB1;
    acc0a = fmaf(eeA0, hA0, acc0a);
    acc1a = fmaf(eeA1, hA1, acc1a);
    acc0b = fmaf(eeB0, hB0, acc0b);
    acc1b = fmaf(eeB1, hB1, acc1b);
  }
  for (; k < end; ++k) {
    int s = col[k];
    float e0 = leaky(as_[s * 2 + 0] + ad0);
    float e1 = leaky(as_[s * 2 + 1] + ad1);
    float ee0 = __expf(e0), ee1 = __expf(e1);
    den0a += ee0; den1a += ee1;
    acc0a = fmaf(ee0, hbuf[(size_t)s * 128 + lane], acc0a);
    acc1a = fmaf(ee1, hbuf[(size_t)s * 128 + 64 + lane], acc1a);
  }
  float acc0 = acc0a + acc0b, acc1 = acc1a + acc1b;
  float den0 = den0a + den0b, den1 = den1a + den1b;
  float o = 0.5f * (acc0 / (den0 + 1e-16f) + acc1 / (den1 + 1e-16f)) + bias[lane];
  out[(size_t)d * 64 + lane] = o;
}

// ---------------- BatchNorm ----------------
__global__ void bn_stats(const float* __restrict__ h, float* __restrict__ stats, int n) {
  __shared__ float ssum[64], ssq[64];
  int t = threadIdx.x;
  if (t < 64) { ssum[t] = 0.f; ssq[t] = 0.f; }
  __syncthreads();
  int c = t & 63;  // stride and start are multiples of 64 -> channel constant
  float lsum = 0.f, lsq = 0.f;
  size_t total = (size_t)n * 64;
  for (size_t i = (size_t)blockIdx.x * blockDim.x + t; i < total;
       i += (size_t)gridDim.x * blockDim.x) {
    float v = h[i];
    lsum += v;
    lsq = fmaf(v, v, lsq);
  }
  atomicAdd(&ssum[c], lsum);
  atomicAdd(&ssq[c], lsq);
  __syncthreads();
  if (t < 64) {
    atomicAdd(&stats[t], ssum[t]);
    atomicAdd(&stats[64 + t], ssq[t]);
  }
}

__global__ void bn_apply(const float* __restrict__ hin, const float* __restrict__ stats,
                         const float* __restrict__ g, const float* __restrict__ be,
                         float* __restrict__ out, int n) {
  size_t i = (size_t)blockIdx.x * blockDim.x + threadIdx.x;
  if (i >= (size_t)n * 64) return;
  int c = (int)(i & 63);
  float inv_n = 1.0f / (float)n;
  float mean = stats[c] * inv_n;
  float var = stats[64 + c] * inv_n - mean * mean;
  float sc = rsqrtf(var + 1e-5f) * g[c];
  float v = (hin[i] - mean) * sc + be[c];
  out[i] = v > 0.f ? v : 0.f;
}

// ---------------- MLP head: one wave per node ----------------
__global__ __launch_bounds__(256) void mlp_head(
    const float* __restrict__ h3, const float* __restrict__ x,
    const float* __restrict__ mW1, const float* __restrict__ mb1,
    const float* __restrict__ mW2, const float* __restrict__ mb2,
    const float* __restrict__ pW, const float* __restrict__ pb,
    const float* __restrict__ vW, const float* __restrict__ vb,
    float* __restrict__ out, int n) {
  int wave = (int)((blockIdx.x * blockDim.x + threadIdx.x) >> 6);
  int lane = threadIdx.x & 63;
  if (wave >= n) return;
  float hval = h3[(size_t)wave * 64 + lane];
  float t1 = mb1[lane];
#pragma unroll 8
  for (int k = 0; k < 64; k++) {
    float a = __shfl(hval, k);
    t1 = fmaf(a, mW1[k * 64 + lane], t1);
  }
  const float* xrow = x + (size_t)wave * 16;
#pragma unroll
  for (int j = 0; j < 5; j++) t1 = fmaf(xrow[9 + j], mW1[(64 + j) * 64 + lane], t1);
  t1 = fmaxf(t1, 0.f);
  float u = mb2[lane];
#pragma unroll 8
  for (int k = 0; k < 64; k++) {
    float a = __shfl(t1, k);
    u = fmaf(a, mW2[k * 64 + lane], u);
  }
  float pl = u * pW[lane];
  float vl = u * vW[lane];
  for (int off = 32; off; off >>= 1) {
    pl += __shfl_down(pl, off);
    vl += __shfl_down(vl, off);
  }
  if (lane == 0) {
    out[wave] = pl + pb[0];
    out[n + wave] = vl + vb[0];
  }
}

extern "C" void kernel_launch(void* const* d_in, const int* in_sizes, int n_in,
                              void* d_out, int out_size, void* d_ws, size_t ws_size,
                              hipStream_t stream) {
  const float* x = (const float*)d_in[0];
  const int* ei = (const int*)d_in[1];
  const float* W[3]  = {(const float*)d_in[2],  (const float*)d_in[8],  (const float*)d_in[14]};
  const float* AS[3] = {(const float*)d_in[3],  (const float*)d_in[9],  (const float*)d_in[15]};
  const float* AD[3] = {(const float*)d_in[4],  (const float*)d_in[10], (const float*)d_in[16]};
  const float* B[3]  = {(const float*)d_in[5],  (const float*)d_in[11], (const float*)d_in[17]};
  const float* G[3]  = {(const float*)d_in[6],  (const float*)d_in[12], (const float*)d_in[18]};
  const float* BE[3] = {(const float*)d_in[7],  (const float*)d_in[13], (const float*)d_in[19]};
  const float* mW1 = (const float*)d_in[20];
  const float* mb1 = (const float*)d_in[21];
  const float* mW2 = (const float*)d_in[22];
  const float* mb2 = (const float*)d_in[23];
  const float* pW  = (const float*)d_in[24];
  const float* pb  = (const float*)d_in[25];
  const float* vW  = (const float*)d_in[26];
  const float* vb  = (const float*)d_in[27];

  const int N = in_sizes[0] / 16;
  const int E = in_sizes[1] / 2;
  const int* srcp = ei;
  const int* dstp = ei + E;

  // workspace carve-up (~110 MB)
  float* bufA  = (float*)d_ws;               // N*64  activations (layer in/out)
  float* bufB  = bufA + (size_t)N * 64;      // N*64  pre-BN aggregation output
  float* hbuf  = bufB + (size_t)N * 64;      // N*128 projected features
  float* as_   = hbuf + (size_t)N * 128;     // N*2
  float* ad_   = as_ + (size_t)N * 2;        // N*2
  float* stats = ad_ + (size_t)N * 2;        // 128
  int* row_ptr = (int*)(stats + 128);        // N+1
  int* cursor  = row_ptr + (N + 1);          // N
  int* colbuf  = cursor + N;                 // E
  int* bsum    = colbuf + E;                 // 256
  int* boff    = bsum + 256;                 // 256

  const int nb = (N + 511) / 512;            // scan blocks (196 for N=100k)

  // ---- CSR build (graph identical each call; rebuilt since inputs re-poisoned)
  hipMemsetAsync(cursor, 0, sizeof(int) * (size_t)N, stream);
  hist_kernel<<<(E + 255) / 256, 256, 0, stream>>>(dstp, cursor, E);
  scan_phase1<<<nb, 256, 0, stream>>>(cursor, bsum, N);
  scan_phase2<<<1, 256, 0, stream>>>(bsum, boff, row_ptr + N, nb);
  scan_phase3<<<nb, 256, 0, stream>>>(cursor, boff, row_ptr, N);
  copy_kernel<<<(N + 255) / 256, 256, 0, stream>>>(row_ptr, cursor, N);
  scatter_kernel<<<(E + 255) / 256, 256, 0, stream>>>(srcp, dstp, cursor, colbuf, E);

  // ---- 3 GAT layers
  const float* in = x;
  int K = 16;
  for (int l = 0; l < 3; l++) {
    gat_project<<<N, 128, 0, stream>>>(in, W[l], AS[l], AD[l], hbuf, as_, ad_, K);
    gat_aggregate<<<(N + 3) / 4, 256, 0, stream>>>(hbuf, as_, ad_, row_ptr, colbuf, B[l], bufB, N);
    hipMemsetAsync(stats, 0, sizeof(float) * 128, stream);
    bn_stats<<<1024, 256, 0, stream>>>(bufB, stats, N);
    bn_apply<<<(N * 64 + 255) / 256, 256, 0, stream>>>(bufB, stats, G[l], BE[l], bufA, N);
    in = bufA;
    K = 64;
  }

  // ---- MLP head -> (logits, value)
  mlp_head<<<(N + 3) / 4, 256, 0, stream>>>(bufA, x, mW1, mb1, mW2, mb2,
                                            pW, pb, vW, vb, (float*)d_out, N);
}

// Round 4
// 934.503 us; speedup vs baseline: 1.4273x; 1.1046x over previous
//
#include <hip/hip_runtime.h>

// N=100000 nodes, E=1000000 edges, D_IN=16, H=2, C=64.
// 3x (GAT -> BN -> ReLU), then MLP head -> (logits, value) concat in d_out.

__device__ __forceinline__ float leaky(float x) { return x > 0.f ? x : 0.2f * x; }

// ---------------- CSR build (dst-sorted; self-loops implicit) ----------------
__global__ void hist_kernel(const int* __restrict__ dst, int* __restrict__ deg, int E) {
  int e = blockIdx.x * blockDim.x + threadIdx.x;
  if (e < E) atomicAdd(&deg[dst[e]], 1);
}

// ---- multi-block exclusive scan: phase 1 (per-block partial sums) ----
__global__ void scan_phase1(const int* __restrict__ deg, int* __restrict__ bsum, int n) {
  __shared__ int red[256];
  int t = threadIdx.x;
  int i0 = blockIdx.x * 512 + t * 2;
  int d0 = (i0 < n) ? deg[i0] : 0;
  int d1 = (i0 + 1 < n) ? deg[i0 + 1] : 0;
  red[t] = d0 + d1;
  __syncthreads();
  for (int off = 128; off; off >>= 1) {
    if (t < off) red[t] += red[t + off];
    __syncthreads();
  }
  if (t == 0) bsum[blockIdx.x] = red[0];
}

__global__ void scan_phase2(const int* __restrict__ bsum, int* __restrict__ boff,
                            int* __restrict__ row_ptr_last, int nb) {
  __shared__ int temp[256];
  int t = threadIdx.x;
  int v = (t < nb) ? bsum[t] : 0;
  temp[t] = v;
  __syncthreads();
  for (int off = 1; off < 256; off <<= 1) {
    int add = (t >= off) ? temp[t - off] : 0;
    __syncthreads();
    temp[t] += add;
    __syncthreads();
  }
  if (t < nb) boff[t] = temp[t] - v;           // exclusive
  if (t == nb - 1) *row_ptr_last = temp[t];    // grand total -> row_ptr[N]
}

__global__ void scan_phase3(const int* __restrict__ deg, const int* __restrict__ boff,
                            int* __restrict__ row_ptr, int n) {
  __shared__ int temp[256];
  int t = threadIdx.x;
  int i0 = blockIdx.x * 512 + t * 2;
  int d0 = (i0 < n) ? deg[i0] : 0;
  int d1 = (i0 + 1 < n) ? deg[i0 + 1] : 0;
  int pair = d0 + d1;
  temp[t] = pair;
  __syncthreads();
  for (int off = 1; off < 256; off <<= 1) {
    int add = (t >= off) ? temp[t - off] : 0;
    __syncthreads();
    temp[t] += add;
    __syncthreads();
  }
  int excl = boff[blockIdx.x] + temp[t] - pair;
  if (i0 < n) row_ptr[i0] = excl;
  if (i0 + 1 < n) row_ptr[i0 + 1] = excl + d0;
}

__global__ void copy_kernel(const int* __restrict__ a, int* __restrict__ b, int n) {
  int i = blockIdx.x * blockDim.x + threadIdx.x;
  if (i < n) b[i] = a[i];
}

__global__ void scatter_kernel(const int* __restrict__ src, const int* __restrict__ dst,
                               int* __restrict__ cursor, int* __restrict__ col, int E) {
  int e = blockIdx.x * blockDim.x + threadIdx.x;
  if (e < E) {
    int d = dst[e];
    int pos = atomicAdd(&cursor[d], 1);
    col[pos] = src[e];
  }
}

// ---------------- GAT projection: h = act @ W (K x 128), + a_s/a_d ----------
__global__ void gat_project(const float* __restrict__ act, const float* __restrict__ W,
                            const float* __restrict__ att_s, const float* __restrict__ att_d,
                            float* __restrict__ hbuf, float* __restrict__ as_,
                            float* __restrict__ ad_, int K) {
  int n = blockIdx.x;
  int t = threadIdx.x;            // 0..127
  int head = t >> 6, lane = t & 63;
  const float* arow = act + (size_t)n * K;
  float sum = 0.f;
#pragma unroll 8
  for (int k = 0; k < K; k++) sum = fmaf(arow[k], W[k * 128 + t], sum);
  hbuf[(size_t)n * 128 + t] = sum;
  float ps = sum * att_s[t];
  float pd = sum * att_d[t];
  for (int off = 32; off; off >>= 1) {
    ps += __shfl_down(ps, off);
    pd += __shfl_down(pd, off);
  }
  if (lane == 0) { as_[n * 2 + head] = ps; ad_[n * 2 + head] = pd; }
}

// ---------------- GAT aggregation: one wave per dst node ---------------------
__global__ __launch_bounds__(256) void gat_aggregate(
    const float* __restrict__ hbuf, const float* __restrict__ as_,
    const float* __restrict__ ad_, const int* __restrict__ row_ptr,
    const int* __restrict__ col, const float* __restrict__ bias,
    float* __restrict__ out, int n) {
  int wave = (int)((blockIdx.x * blockDim.x + threadIdx.x) >> 6);
  int lane = threadIdx.x & 63;
  if (wave >= n) return;
  int d = wave;
  int beg = row_ptr[d], end = row_ptr[d + 1];
  float ad0 = ad_[d * 2 + 0], ad1 = ad_[d * 2 + 1];
  float acc0a, acc1a, den0a, den1a;
  {
    float ee0 = __expf(leaky(as_[d * 2 + 0] + ad0));
    float ee1 = __expf(leaky(as_[d * 2 + 1] + ad1));
    den0a = ee0; den1a = ee1;
    acc0a = ee0 * hbuf[(size_t)d * 128 + lane];
    acc1a = ee1 * hbuf[(size_t)d * 128 + 64 + lane];
  }
  float acc0b = 0.f, acc1b = 0.f, den0b = 0.f, den1b = 0.f;
  int k = beg;
  for (; k + 1 < end; k += 2) {
    int sA = col[k], sB = col[k + 1];
    float eA0 = leaky(as_[sA * 2 + 0] + ad0);
    float eA1 = leaky(as_[sA * 2 + 1] + ad1);
    float eB0 = leaky(as_[sB * 2 + 0] + ad0);
    float eB1 = leaky(as_[sB * 2 + 1] + ad1);
    float hA0 = hbuf[(size_t)sA * 128 + lane];
    float hA1 = hbuf[(size_t)sA * 128 + 64 + lane];
    float hB0 = hbuf[(size_t)sB * 128 + lane];
    float hB1 = hbuf[(size_t)sB * 128 + 64 + lane];
    float eeA0 = __expf(eA0), eeA1 = __expf(eA1);
    float eeB0 = __expf(eB0), eeB1 = __expf(eB1);
    den0a += eeA0; den1a += eeA1;
    den0b += eeB0; den1b += eeB1;
    acc0a = fmaf(eeA0, hA0, acc0a);
    acc1a = fmaf(eeA1, hA1, acc1a);
    acc0b = fmaf(eeB0, hB0, acc0b);
    acc1b = fmaf(eeB1, hB1, acc1b);
  }
  for (; k < end; ++k) {
    int s = col[k];
    float e0 = leaky(as_[s * 2 + 0] + ad0);
    float e1 = leaky(as_[s * 2 + 1] + ad1);
    float ee0 = __expf(e0), ee1 = __expf(e1);
    den0a += ee0; den1a += ee1;
    acc0a = fmaf(ee0, hbuf[(size_t)s * 128 + lane], acc0a);
    acc1a = fmaf(ee1, hbuf[(size_t)s * 128 + 64 + lane], acc1a);
  }
  float acc0 = acc0a + acc0b, acc1 = acc1a + acc1b;
  float den0 = den0a + den0b, den1 = den1a + den1b;
  float o = 0.5f * (acc0 / (den0 + 1e-16f) + acc1 / (den1 + 1e-16f)) + bias[lane];
  out[(size_t)d * 64 + lane] = o;
}

// ---------------- BatchNorm ----------------
__global__ void bn_stats(const float* __restrict__ h, float* __restrict__ stats, int n) {
  __shared__ float ssum[64], ssq[64];
  int t = threadIdx.x;
  if (t < 64) { ssum[t] = 0.f; ssq[t] = 0.f; }
  __syncthreads();
  int c = t & 63;
  float lsum = 0.f, lsq = 0.f;
  size_t total = (size_t)n * 64;
  for (size_t i = (size_t)blockIdx.x * blockDim.x + t; i < total;
       i += (size_t)gridDim.x * blockDim.x) {
    float v = h[i];
    lsum += v;
    lsq = fmaf(v, v, lsq);
  }
  atomicAdd(&ssum[c], lsum);
  atomicAdd(&ssq[c], lsq);
  __syncthreads();
  if (t < 64) {
    atomicAdd(&stats[t], ssum[t]);
    atomicAdd(&stats[64 + t], ssq[t]);
  }
}

__global__ void bn_apply(const float* __restrict__ hin, const float* __restrict__ stats,
                         const float* __restrict__ g, const float* __restrict__ be,
                         float* __restrict__ out, int n) {
  size_t i = (size_t)blockIdx.x * blockDim.x + threadIdx.x;
  if (i >= (size_t)n * 64) return;
  int c = (int)(i & 63);
  float inv_n = 1.0f / (float)n;
  float mean = stats[c] * inv_n;
  float var = stats[64 + c] * inv_n - mean * mean;
  float sc = rsqrtf(var + 1e-5f) * g[c];
  float v = (hin[i] - mean) * sc + be[c];
  out[i] = v > 0.f ? v : 0.f;
}

// ---------------- MLP head: fused tiled GEMM (64 nodes / block) --------------
// h = relu(concat(h3,ctx) @ mW1 + mb1) @ mW2 + mb2; logits=h@pW+pb; value=h@vW+vb
// LDS (floats): a1[64x68] h3-tile | ctx[64x8] | a2[64x68] t1-tile | w1[69x64]
// w2 (64x64) aliases a1 after GEMM1.  Total 54528 B -> 3 blocks/CU.
__global__ __launch_bounds__(256) void mlp_head_tiled(
    const float* __restrict__ h3, const float* __restrict__ x,
    const float* __restrict__ mW1, const float* __restrict__ mb1,
    const float* __restrict__ mW2, const float* __restrict__ mb2,
    const float* __restrict__ pW, const float* __restrict__ pb,
    const float* __restrict__ vW, const float* __restrict__ vb,
    float* __restrict__ out, int n) {
  __shared__ float lds[13632];
  float* a1  = lds;           // 64*68 = 4352
  float* ctx = lds + 4352;    // 64*8  = 512
  float* a2  = lds + 4864;    // 64*68 = 4352
  float* w1  = lds + 9216;    // 69*64 = 4416
  float* w2  = lds;           // aliases a1 (dead after GEMM1)

  int t = threadIdx.x;
  int node0 = blockIdx.x * 64;
  int rows = min(64, n - node0);

  // stage h3 tile (64x64, float4, stride 68 to dodge bank conflicts)
#pragma unroll
  for (int i = 0; i < 4; i++) {
    int flat = t + i * 256;          // float4 index in [0,1024)
    int r = flat >> 4, kc = flat & 15;
    float4 v = make_float4(0.f, 0.f, 0.f, 0.f);
    if (r < rows) v = *(const float4*)&h3[(size_t)(node0 + r) * 64 + kc * 4];
    *(float4*)&a1[r * 68 + kc * 4] = v;
  }
  // stage ctx (x[:,9:14], 64x5) -- 320 slots, MUST grid-stride with 256 threads
  for (int i = t; i < 320; i += 256) {
    int r = i / 5, j = i % 5;
    ctx[r * 8 + j] = (r < rows) ? x[(size_t)(node0 + r) * 16 + 9 + j] : 0.f;
  }
  // stage w1 (69x64 = 1104 float4)
#pragma unroll
  for (int i = 0; i < 5; i++) {
    int flat = t + i * 256;
    if (flat < 1104) *(float4*)&w1[flat * 4] = *(const float4*)&mW1[flat * 4];
  }
  __syncthreads();

  int tc = t & 15, tr = t >> 4;
  int c0 = tc * 4, r0 = tr * 4;

  // ---- GEMM1: t1 = relu(a1|ctx @ w1 + mb1), 4x4 per thread ----
  float acc[4][4] = {};
  for (int k = 0; k < 64; k += 4) {
    float4 av[4], wv[4];
#pragma unroll
    for (int i = 0; i < 4; i++) av[i] = *(const float4*)&a1[(r0 + i) * 68 + k];
#pragma unroll
    for (int j = 0; j < 4; j++) wv[j] = *(const float4*)&w1[(k + j) * 64 + c0];
#pragma unroll
    for (int i = 0; i < 4; i++) {
      const float* ai = (const float*)&av[i];
#pragma unroll
      for (int kk = 0; kk < 4; kk++) {
        const float* wr = (const float*)&wv[kk];
        acc[i][0] = fmaf(ai[kk], wr[0], acc[i][0]);
        acc[i][1] = fmaf(ai[kk], wr[1], acc[i][1]);
        acc[i][2] = fmaf(ai[kk], wr[2], acc[i][2]);
        acc[i][3] = fmaf(ai[kk], wr[3], acc[i][3]);
      }
    }
  }
#pragma unroll
  for (int k = 64; k < 69; k++) {
    float4 wv = *(const float4*)&w1[k * 64 + c0];
    const float* wr = (const float*)&wv;
#pragma unroll
    for (int i = 0; i < 4; i++) {
      float a = ctx[(r0 + i) * 8 + (k - 64)];
      acc[i][0] = fmaf(a, wr[0], acc[i][0]);
      acc[i][1] = fmaf(a, wr[1], acc[i][1]);
      acc[i][2] = fmaf(a, wr[2], acc[i][2]);
      acc[i][3] = fmaf(a, wr[3], acc[i][3]);
    }
  }
  float b1v0 = mb1[c0], b1v1 = mb1[c0 + 1], b1v2 = mb1[c0 + 2], b1v3 = mb1[c0 + 3];
#pragma unroll
  for (int i = 0; i < 4; i++) {
    float4 t1;
    t1.x = fmaxf(acc[i][0] + b1v0, 0.f);
    t1.y = fmaxf(acc[i][1] + b1v1, 0.f);
    t1.z = fmaxf(acc[i][2] + b1v2, 0.f);
    t1.w = fmaxf(acc[i][3] + b1v3, 0.f);
    *(float4*)&a2[(r0 + i) * 68 + c0] = t1;
  }
  __syncthreads();   // GEMM1 reads done + t1 visible

  // stage w2 over the dead a1 region (64x64 = 1024 float4)
#pragma unroll
  for (int i = 0; i < 4; i++) {
    int flat = t + i * 256;
    *(float4*)&w2[flat * 4] = *(const float4*)&mW2[flat * 4];
  }
  __syncthreads();

  // ---- GEMM2: u = t1 @ w2 + mb2 ----
  float acc2[4][4] = {};
  for (int k = 0; k < 64; k += 4) {
    float4 av[4], wv[4];
#pragma unroll
    for (int i = 0; i < 4; i++) av[i] = *(const float4*)&a2[(r0 + i) * 68 + k];
#pragma unroll
    for (int j = 0; j < 4; j++) wv[j] = *(const float4*)&w2[(k + j) * 64 + c0];
#pragma unroll
    for (int i = 0; i < 4; i++) {
      const float* ai = (const float*)&av[i];
#pragma unroll
      for (int kk = 0; kk < 4; kk++) {
        const float* wr = (const float*)&wv[kk];
        acc2[i][0] = fmaf(ai[kk], wr[0], acc2[i][0]);
        acc2[i][1] = fmaf(ai[kk], wr[1], acc2[i][1]);
        acc2[i][2] = fmaf(ai[kk], wr[2], acc2[i][2]);
        acc2[i][3] = fmaf(ai[kk], wr[3], acc2[i][3]);
      }
    }
  }

  // ---- heads: p = u . pW, v = u . vW; reduce over the 16 tc groups ----
  float b2v[4], pwv[4], vwv[4];
#pragma unroll
  for (int j = 0; j < 4; j++) {
    b2v[j] = mb2[c0 + j];
    pwv[j] = pW[c0 + j];
    vwv[j] = vW[c0 + j];
  }
  float p[4], v[4];
#pragma unroll
  for (int i = 0; i < 4; i++) {
    float ps = 0.f, vs = 0.f;
#pragma unroll
    for (int j = 0; j < 4; j++) {
      float u = acc2[i][j] + b2v[j];
      ps = fmaf(u, pwv[j], ps);
      vs = fmaf(u, vwv[j], vs);
    }
    p[i] = ps; v[i] = vs;
  }
#pragma unroll
  for (int off = 1; off < 16; off <<= 1) {
#pragma unroll
    for (int i = 0; i < 4; i++) {
      p[i] += __shfl_xor(p[i], off);
      v[i] += __shfl_xor(v[i], off);
    }
  }
  if (tc == 0) {
    float pbs = pb[0], vbs = vb[0];
#pragma unroll
    for (int i = 0; i < 4; i++) {
      int r = r0 + i;
      if (r < rows) {
        out[node0 + r] = p[i] + pbs;
        out[n + node0 + r] = v[i] + vbs;
      }
    }
  }
}

extern "C" void kernel_launch(void* const* d_in, const int* in_sizes, int n_in,
                              void* d_out, int out_size, void* d_ws, size_t ws_size,
                              hipStream_t stream) {
  const float* x = (const float*)d_in[0];
  const int* ei = (const int*)d_in[1];
  const float* W[3]  = {(const float*)d_in[2],  (const float*)d_in[8],  (const float*)d_in[14]};
  const float* AS[3] = {(const float*)d_in[3],  (const float*)d_in[9],  (const float*)d_in[15]};
  const float* AD[3] = {(const float*)d_in[4],  (const float*)d_in[10], (const float*)d_in[16]};
  const float* B[3]  = {(const float*)d_in[5],  (const float*)d_in[11], (const float*)d_in[17]};
  const float* G[3]  = {(const float*)d_in[6],  (const float*)d_in[12], (const float*)d_in[18]};
  const float* BE[3] = {(const float*)d_in[7],  (const float*)d_in[13], (const float*)d_in[19]};
  const float* mW1 = (const float*)d_in[20];
  const float* mb1 = (const float*)d_in[21];
  const float* mW2 = (const float*)d_in[22];
  const float* mb2 = (const float*)d_in[23];
  const float* pW  = (const float*)d_in[24];
  const float* pb  = (const float*)d_in[25];
  const float* vW  = (const float*)d_in[26];
  const float* vb  = (const float*)d_in[27];

  const int N = in_sizes[0] / 16;
  const int E = in_sizes[1] / 2;
  const int* srcp = ei;
  const int* dstp = ei + E;

  // workspace carve-up (~110 MB)
  float* bufA  = (float*)d_ws;               // N*64  activations (layer in/out)
  float* bufB  = bufA + (size_t)N * 64;      // N*64  pre-BN aggregation output
  float* hbuf  = bufB + (size_t)N * 64;      // N*128 projected features
  float* as_   = hbuf + (size_t)N * 128;     // N*2
  float* ad_   = as_ + (size_t)N * 2;        // N*2
  float* stats = ad_ + (size_t)N * 2;        // 128
  int* row_ptr = (int*)(stats + 128);        // N+1
  int* cursor  = row_ptr + (N + 1);          // N
  int* colbuf  = cursor + N;                 // E
  int* bsum    = colbuf + E;                 // 256
  int* boff    = bsum + 256;                 // 256

  const int nb = (N + 511) / 512;

  // ---- CSR build
  hipMemsetAsync(cursor, 0, sizeof(int) * (size_t)N, stream);
  hist_kernel<<<(E + 255) / 256, 256, 0, stream>>>(dstp, cursor, E);
  scan_phase1<<<nb, 256, 0, stream>>>(cursor, bsum, N);
  scan_phase2<<<1, 256, 0, stream>>>(bsum, boff, row_ptr + N, nb);
  scan_phase3<<<nb, 256, 0, stream>>>(cursor, boff, row_ptr, N);
  copy_kernel<<<(N + 255) / 256, 256, 0, stream>>>(row_ptr, cursor, N);
  scatter_kernel<<<(E + 255) / 256, 256, 0, stream>>>(srcp, dstp, cursor, colbuf, E);

  // ---- 3 GAT layers
  const float* in = x;
  int K = 16;
  for (int l = 0; l < 3; l++) {
    gat_project<<<N, 128, 0, stream>>>(in, W[l], AS[l], AD[l], hbuf, as_, ad_, K);
    gat_aggregate<<<(N + 3) / 4, 256, 0, stream>>>(hbuf, as_, ad_, row_ptr, colbuf, B[l], bufB, N);
    hipMemsetAsync(stats, 0, sizeof(float) * 128, stream);
    bn_stats<<<1024, 256, 0, stream>>>(bufB, stats, N);
    bn_apply<<<(N * 64 + 255) / 256, 256, 0, stream>>>(bufB, stats, G[l], BE[l], bufA, N);
    in = bufA;
    K = 64;
  }

  // ---- MLP head -> (logits, value)
  mlp_head_tiled<<<(N + 63) / 64, 256, 0, stream>>>(bufA, x, mW1, mb1, mW2, mb2,
                                                    pW, pb, vW, vb, (float*)d_out, N);
}

// Round 5
// 773.849 us; speedup vs baseline: 1.7236x; 1.2076x over previous
//
#include <hip/hip_runtime.h>

// N=100000 nodes, E=1000000 edges, D_IN=16, H=2, C=64.
// 3x (GAT -> BN -> ReLU), then MLP head -> (logits, value) concat in d_out.

__device__ __forceinline__ float leaky(float x) { return x > 0.f ? x : 0.2f * x; }

// ---------------- CSR build (dst-sorted; self-loops implicit) ----------------
__global__ void hist_kernel(const int* __restrict__ dst, int* __restrict__ deg, int E) {
  int e = blockIdx.x * blockDim.x + threadIdx.x;
  if (e < E) atomicAdd(&deg[dst[e]], 1);
}

__global__ void scan_phase1(const int* __restrict__ deg, int* __restrict__ bsum, int n) {
  __shared__ int red[256];
  int t = threadIdx.x;
  int i0 = blockIdx.x * 512 + t * 2;
  int d0 = (i0 < n) ? deg[i0] : 0;
  int d1 = (i0 + 1 < n) ? deg[i0 + 1] : 0;
  red[t] = d0 + d1;
  __syncthreads();
  for (int off = 128; off; off >>= 1) {
    if (t < off) red[t] += red[t + off];
    __syncthreads();
  }
  if (t == 0) bsum[blockIdx.x] = red[0];
}

__global__ void scan_phase2(const int* __restrict__ bsum, int* __restrict__ boff,
                            int* __restrict__ row_ptr_last, int nb) {
  __shared__ int temp[256];
  int t = threadIdx.x;
  int v = (t < nb) ? bsum[t] : 0;
  temp[t] = v;
  __syncthreads();
  for (int off = 1; off < 256; off <<= 1) {
    int add = (t >= off) ? temp[t - off] : 0;
    __syncthreads();
    temp[t] += add;
    __syncthreads();
  }
  if (t < nb) boff[t] = temp[t] - v;           // exclusive
  if (t == nb - 1) *row_ptr_last = temp[t];    // grand total -> row_ptr[N]
}

__global__ void scan_phase3(const int* __restrict__ deg, const int* __restrict__ boff,
                            int* __restrict__ row_ptr, int n) {
  __shared__ int temp[256];
  int t = threadIdx.x;
  int i0 = blockIdx.x * 512 + t * 2;
  int d0 = (i0 < n) ? deg[i0] : 0;
  int d1 = (i0 + 1 < n) ? deg[i0 + 1] : 0;
  int pair = d0 + d1;
  temp[t] = pair;
  __syncthreads();
  for (int off = 1; off < 256; off <<= 1) {
    int add = (t >= off) ? temp[t - off] : 0;
    __syncthreads();
    temp[t] += add;
    __syncthreads();
  }
  int excl = boff[blockIdx.x] + temp[t] - pair;
  if (i0 < n) row_ptr[i0] = excl;
  if (i0 + 1 < n) row_ptr[i0 + 1] = excl + d0;
}

__global__ void copy_kernel(const int* __restrict__ a, int* __restrict__ b, int n) {
  int i = blockIdx.x * blockDim.x + threadIdx.x;
  if (i < n) b[i] = a[i];
}

__global__ void scatter_kernel(const int* __restrict__ src, const int* __restrict__ dst,
                               int* __restrict__ cursor, int* __restrict__ col, int E) {
  int e = blockIdx.x * blockDim.x + threadIdx.x;
  if (e < E) {
    int d = dst[e];
    int pos = atomicAdd(&cursor[d], 1);
    col[pos] = src[e];
  }
}

// ---------------- GAT projection: LDS-tiled GEMM, 64 nodes x 128 cols -------
// h = act @ W (N x K @ K x 128); a_s = (h*att_s).sum per head; same a_d.
// 256 threads, 4 rows x 8 cols per thread. LDS: A[64x(K+4)] + W[Kx128] + att[256].
template <int K>
__global__ __launch_bounds__(256) void gat_project_tiled(
    const float* __restrict__ act, const float* __restrict__ W,
    const float* __restrict__ att_s, const float* __restrict__ att_d,
    float* __restrict__ hbuf, float* __restrict__ as_,
    float* __restrict__ ad_, int n) {
  constexpr int AST = K + 4;
  __shared__ float aS[64 * AST];
  __shared__ float wS[K * 128];
  __shared__ float attS[256];

  int t = threadIdx.x;
  int node0 = blockIdx.x * 64;
  int rows = min(64, n - node0);

  // stage A tile (64 x K, float4, padded stride)
  constexpr int AF4 = 64 * K / 4;
  for (int i = t; i < AF4; i += 256) {
    int r = i / (K / 4), kc = i % (K / 4);
    float4 v = make_float4(0.f, 0.f, 0.f, 0.f);
    if (r < rows) v = *(const float4*)&act[(size_t)(node0 + r) * K + kc * 4];
    *(float4*)&aS[r * AST + kc * 4] = v;
  }
  // stage W (K x 128)
  constexpr int WF4 = K * 32;
  for (int i = t; i < WF4; i += 256)
    *(float4*)&wS[i * 4] = *(const float4*)&W[i * 4];
  // stage att vectors
  attS[t] = (t < 128) ? att_s[t] : att_d[t - 128];
  __syncthreads();

  int tc = t & 15, tr = t >> 4;
  int c0 = tc * 8, r0 = tr * 4;

  float acc[4][8] = {};
  for (int k = 0; k < K; k += 4) {
    float4 av[4];
    float4 wv[4][2];
#pragma unroll
    for (int i = 0; i < 4; i++) av[i] = *(const float4*)&aS[(r0 + i) * AST + k];
#pragma unroll
    for (int kk = 0; kk < 4; kk++) {
      wv[kk][0] = *(const float4*)&wS[(k + kk) * 128 + c0];
      wv[kk][1] = *(const float4*)&wS[(k + kk) * 128 + c0 + 4];
    }
#pragma unroll
    for (int i = 0; i < 4; i++) {
      const float* ai = (const float*)&av[i];
#pragma unroll
      for (int kk = 0; kk < 4; kk++) {
        const float* w0 = (const float*)&wv[kk][0];
        const float* w1 = (const float*)&wv[kk][1];
#pragma unroll
        for (int j = 0; j < 4; j++) {
          acc[i][j] = fmaf(ai[kk], w0[j], acc[i][j]);
          acc[i][4 + j] = fmaf(ai[kk], w1[j], acc[i][4 + j]);
        }
      }
    }
  }

  // epilogue: store h, compute a_s/a_d partials and reduce over col groups
#pragma unroll
  for (int i = 0; i < 4; i++) {
    int r = r0 + i;
    float psv = 0.f, pdv = 0.f;
#pragma unroll
    for (int j = 0; j < 8; j++) {
      psv = fmaf(acc[i][j], attS[c0 + j], psv);
      pdv = fmaf(acc[i][j], attS[128 + c0 + j], pdv);
    }
    // reduce within each head-half (tc 0..7 / 8..15); lanes differ in bits 0..3
    psv += __shfl_xor(psv, 1); pdv += __shfl_xor(pdv, 1);
    psv += __shfl_xor(psv, 2); pdv += __shfl_xor(pdv, 2);
    psv += __shfl_xor(psv, 4); pdv += __shfl_xor(pdv, 4);
    if (r < rows) {
      *(float4*)&hbuf[(size_t)(node0 + r) * 128 + c0] =
          make_float4(acc[i][0], acc[i][1], acc[i][2], acc[i][3]);
      *(float4*)&hbuf[(size_t)(node0 + r) * 128 + c0 + 4] =
          make_float4(acc[i][4], acc[i][5], acc[i][6], acc[i][7]);
      if (tc == 0 || tc == 8) {
        int head = tc >> 3;
        as_[(node0 + r) * 2 + head] = psv;
        ad_[(node0 + r) * 2 + head] = pdv;
      }
    }
  }
}

// ---------------- GAT aggregation: one wave per dst node ---------------------
__global__ __launch_bounds__(256) void gat_aggregate(
    const float* __restrict__ hbuf, const float* __restrict__ as_,
    const float* __restrict__ ad_, const int* __restrict__ row_ptr,
    const int* __restrict__ col, const float* __restrict__ bias,
    float* __restrict__ out, int n) {
  int wave = (int)((blockIdx.x * blockDim.x + threadIdx.x) >> 6);
  int lane = threadIdx.x & 63;
  if (wave >= n) return;
  int d = wave;
  int beg = row_ptr[d], end = row_ptr[d + 1];
  float ad0 = ad_[d * 2 + 0], ad1 = ad_[d * 2 + 1];
  float acc0a, acc1a, den0a, den1a;
  {
    float ee0 = __expf(leaky(as_[d * 2 + 0] + ad0));
    float ee1 = __expf(leaky(as_[d * 2 + 1] + ad1));
    den0a = ee0; den1a = ee1;
    acc0a = ee0 * hbuf[(size_t)d * 128 + lane];
    acc1a = ee1 * hbuf[(size_t)d * 128 + 64 + lane];
  }
  float acc0b = 0.f, acc1b = 0.f, den0b = 0.f, den1b = 0.f;
  int k = beg;
  for (; k + 1 < end; k += 2) {
    int sA = col[k], sB = col[k + 1];
    float eA0 = leaky(as_[sA * 2 + 0] + ad0);
    float eA1 = leaky(as_[sA * 2 + 1] + ad1);
    float eB0 = leaky(as_[sB * 2 + 0] + ad0);
    float eB1 = leaky(as_[sB * 2 + 1] + ad1);
    float hA0 = hbuf[(size_t)sA * 128 + lane];
    float hA1 = hbuf[(size_t)sA * 128 + 64 + lane];
    float hB0 = hbuf[(size_t)sB * 128 + lane];
    float hB1 = hbuf[(size_t)sB * 128 + 64 + lane];
    float eeA0 = __expf(eA0), eeA1 = __expf(eA1);
    float eeB0 = __expf(eB0), eeB1 = __expf(eB1);
    den0a += eeA0; den1a += eeA1;
    den0b += eeB0; den1b += eeB1;
    acc0a = fmaf(eeA0, hA0, acc0a);
    acc1a = fmaf(eeA1, hA1, acc1a);
    acc0b = fmaf(eeB0, hB0, acc0b);
    acc1b = fmaf(eeB1, hB1, acc1b);
  }
  for (; k < end; ++k) {
    int s = col[k];
    float e0 = leaky(as_[s * 2 + 0] + ad0);
    float e1 = leaky(as_[s * 2 + 1] + ad1);
    float ee0 = __expf(e0), ee1 = __expf(e1);
    den0a += ee0; den1a += ee1;
    acc0a = fmaf(ee0, hbuf[(size_t)s * 128 + lane], acc0a);
    acc1a = fmaf(ee1, hbuf[(size_t)s * 128 + 64 + lane], acc1a);
  }
  float acc0 = acc0a + acc0b, acc1 = acc1a + acc1b;
  float den0 = den0a + den0b, den1 = den1a + den1b;
  float o = 0.5f * (acc0 / (den0 + 1e-16f) + acc1 / (den1 + 1e-16f)) + bias[lane];
  out[(size_t)d * 64 + lane] = o;
}

// ---------------- BatchNorm ----------------
__global__ void bn_stats(const float* __restrict__ h, float* __restrict__ stats, int n) {
  __shared__ float ssum[64], ssq[64];
  int t = threadIdx.x;
  if (t < 64) { ssum[t] = 0.f; ssq[t] = 0.f; }
  __syncthreads();
  int c = t & 63;
  float lsum = 0.f, lsq = 0.f;
  size_t total = (size_t)n * 64;
  for (size_t i = (size_t)blockIdx.x * blockDim.x + t; i < total;
       i += (size_t)gridDim.x * blockDim.x) {
    float v = h[i];
    lsum += v;
    lsq = fmaf(v, v, lsq);
  }
  atomicAdd(&ssum[c], lsum);
  atomicAdd(&ssq[c], lsq);
  __syncthreads();
  if (t < 64) {
    atomicAdd(&stats[t], ssum[t]);
    atomicAdd(&stats[64 + t], ssq[t]);
  }
}

__global__ void bn_apply(const float* __restrict__ hin, const float* __restrict__ stats,
                         const float* __restrict__ g, const float* __restrict__ be,
                         float* __restrict__ out, int n) {
  size_t i = (size_t)blockIdx.x * blockDim.x + threadIdx.x;
  if (i >= (size_t)n * 64) return;
  int c = (int)(i & 63);
  float inv_n = 1.0f / (float)n;
  float mean = stats[c] * inv_n;
  float var = stats[64 + c] * inv_n - mean * mean;
  float sc = rsqrtf(var + 1e-5f) * g[c];
  float v = (hin[i] - mean) * sc + be[c];
  out[i] = v > 0.f ? v : 0.f;
}

// ---------------- MLP head: fused tiled GEMM (64 nodes / block) --------------
__global__ __launch_bounds__(256) void mlp_head_tiled(
    const float* __restrict__ h3, const float* __restrict__ x,
    const float* __restrict__ mW1, const float* __restrict__ mb1,
    const float* __restrict__ mW2, const float* __restrict__ mb2,
    const float* __restrict__ pW, const float* __restrict__ pb,
    const float* __restrict__ vW, const float* __restrict__ vb,
    float* __restrict__ out, int n) {
  __shared__ float lds[13632];
  float* a1  = lds;           // 64*68 = 4352
  float* ctx = lds + 4352;    // 64*8  = 512
  float* a2  = lds + 4864;    // 64*68 = 4352
  float* w1  = lds + 9216;    // 69*64 = 4416
  float* w2  = lds;           // aliases a1 (dead after GEMM1)

  int t = threadIdx.x;
  int node0 = blockIdx.x * 64;
  int rows = min(64, n - node0);

#pragma unroll
  for (int i = 0; i < 4; i++) {
    int flat = t + i * 256;
    int r = flat >> 4, kc = flat & 15;
    float4 v = make_float4(0.f, 0.f, 0.f, 0.f);
    if (r < rows) v = *(const float4*)&h3[(size_t)(node0 + r) * 64 + kc * 4];
    *(float4*)&a1[r * 68 + kc * 4] = v;
  }
  for (int i = t; i < 320; i += 256) {
    int r = i / 5, j = i % 5;
    ctx[r * 8 + j] = (r < rows) ? x[(size_t)(node0 + r) * 16 + 9 + j] : 0.f;
  }
#pragma unroll
  for (int i = 0; i < 5; i++) {
    int flat = t + i * 256;
    if (flat < 1104) *(float4*)&w1[flat * 4] = *(const float4*)&mW1[flat * 4];
  }
  __syncthreads();

  int tc = t & 15, tr = t >> 4;
  int c0 = tc * 4, r0 = tr * 4;

  float acc[4][4] = {};
  for (int k = 0; k < 64; k += 4) {
    float4 av[4], wv[4];
#pragma unroll
    for (int i = 0; i < 4; i++) av[i] = *(const float4*)&a1[(r0 + i) * 68 + k];
#pragma unroll
    for (int j = 0; j < 4; j++) wv[j] = *(const float4*)&w1[(k + j) * 64 + c0];
#pragma unroll
    for (int i = 0; i < 4; i++) {
      const float* ai = (const float*)&av[i];
#pragma unroll
      for (int kk = 0; kk < 4; kk++) {
        const float* wr = (const float*)&wv[kk];
        acc[i][0] = fmaf(ai[kk], wr[0], acc[i][0]);
        acc[i][1] = fmaf(ai[kk], wr[1], acc[i][1]);
        acc[i][2] = fmaf(ai[kk], wr[2], acc[i][2]);
        acc[i][3] = fmaf(ai[kk], wr[3], acc[i][3]);
      }
    }
  }
#pragma unroll
  for (int k = 64; k < 69; k++) {
    float4 wv = *(const float4*)&w1[k * 64 + c0];
    const float* wr = (const float*)&wv;
#pragma unroll
    for (int i = 0; i < 4; i++) {
      float a = ctx[(r0 + i) * 8 + (k - 64)];
      acc[i][0] = fmaf(a, wr[0], acc[i][0]);
      acc[i][1] = fmaf(a, wr[1], acc[i][1]);
      acc[i][2] = fmaf(a, wr[2], acc[i][2]);
      acc[i][3] = fmaf(a, wr[3], acc[i][3]);
    }
  }
  float b1v0 = mb1[c0], b1v1 = mb1[c0 + 1], b1v2 = mb1[c0 + 2], b1v3 = mb1[c0 + 3];
#pragma unroll
  for (int i = 0; i < 4; i++) {
    float4 t1;
    t1.x = fmaxf(acc[i][0] + b1v0, 0.f);
    t1.y = fmaxf(acc[i][1] + b1v1, 0.f);
    t1.z = fmaxf(acc[i][2] + b1v2, 0.f);
    t1.w = fmaxf(acc[i][3] + b1v3, 0.f);
    *(float4*)&a2[(r0 + i) * 68 + c0] = t1;
  }
  __syncthreads();

#pragma unroll
  for (int i = 0; i < 4; i++) {
    int flat = t + i * 256;
    *(float4*)&w2[flat * 4] = *(const float4*)&mW2[flat * 4];
  }
  __syncthreads();

  float acc2[4][4] = {};
  for (int k = 0; k < 64; k += 4) {
    float4 av[4], wv[4];
#pragma unroll
    for (int i = 0; i < 4; i++) av[i] = *(const float4*)&a2[(r0 + i) * 68 + k];
#pragma unroll
    for (int j = 0; j < 4; j++) wv[j] = *(const float4*)&w2[(k + j) * 64 + c0];
#pragma unroll
    for (int i = 0; i < 4; i++) {
      const float* ai = (const float*)&av[i];
#pragma unroll
      for (int kk = 0; kk < 4; kk++) {
        const float* wr = (const float*)&wv[kk];
        acc2[i][0] = fmaf(ai[kk], wr[0], acc2[i][0]);
        acc2[i][1] = fmaf(ai[kk], wr[1], acc2[i][1]);
        acc2[i][2] = fmaf(ai[kk], wr[2], acc2[i][2]);
        acc2[i][3] = fmaf(ai[kk], wr[3], acc2[i][3]);
      }
    }
  }

  float b2v[4], pwv[4], vwv[4];
#pragma unroll
  for (int j = 0; j < 4; j++) {
    b2v[j] = mb2[c0 + j];
    pwv[j] = pW[c0 + j];
    vwv[j] = vW[c0 + j];
  }
  float p[4], v[4];
#pragma unroll
  for (int i = 0; i < 4; i++) {
    float ps = 0.f, vs = 0.f;
#pragma unroll
    for (int j = 0; j < 4; j++) {
      float u = acc2[i][j] + b2v[j];
      ps = fmaf(u, pwv[j], ps);
      vs = fmaf(u, vwv[j], vs);
    }
    p[i] = ps; v[i] = vs;
  }
#pragma unroll
  for (int off = 1; off < 16; off <<= 1) {
#pragma unroll
    for (int i = 0; i < 4; i++) {
      p[i] += __shfl_xor(p[i], off);
      v[i] += __shfl_xor(v[i], off);
    }
  }
  if (tc == 0) {
    float pbs = pb[0], vbs = vb[0];
#pragma unroll
    for (int i = 0; i < 4; i++) {
      int r = r0 + i;
      if (r < rows) {
        out[node0 + r] = p[i] + pbs;
        out[n + node0 + r] = v[i] + vbs;
      }
    }
  }
}

extern "C" void kernel_launch(void* const* d_in, const int* in_sizes, int n_in,
                              void* d_out, int out_size, void* d_ws, size_t ws_size,
                              hipStream_t stream) {
  const float* x = (const float*)d_in[0];
  const int* ei = (const int*)d_in[1];
  const float* W[3]  = {(const float*)d_in[2],  (const float*)d_in[8],  (const float*)d_in[14]};
  const float* AS[3] = {(const float*)d_in[3],  (const float*)d_in[9],  (const float*)d_in[15]};
  const float* AD[3] = {(const float*)d_in[4],  (const float*)d_in[10], (const float*)d_in[16]};
  const float* B[3]  = {(const float*)d_in[5],  (const float*)d_in[11], (const float*)d_in[17]};
  const float* G[3]  = {(const float*)d_in[6],  (const float*)d_in[12], (const float*)d_in[18]};
  const float* BE[3] = {(const float*)d_in[7],  (const float*)d_in[13], (const float*)d_in[19]};
  const float* mW1 = (const float*)d_in[20];
  const float* mb1 = (const float*)d_in[21];
  const float* mW2 = (const float*)d_in[22];
  const float* mb2 = (const float*)d_in[23];
  const float* pW  = (const float*)d_in[24];
  const float* pb  = (const float*)d_in[25];
  const float* vW  = (const float*)d_in[26];
  const float* vb  = (const float*)d_in[27];

  const int N = in_sizes[0] / 16;
  const int E = in_sizes[1] / 2;
  const int* srcp = ei;
  const int* dstp = ei + E;

  float* bufA  = (float*)d_ws;               // N*64  activations (layer in/out)
  float* bufB  = bufA + (size_t)N * 64;      // N*64  pre-BN aggregation output
  float* hbuf  = bufB + (size_t)N * 64;      // N*128 projected features
  float* as_   = hbuf + (size_t)N * 128;     // N*2
  float* ad_   = as_ + (size_t)N * 2;        // N*2
  float* stats = ad_ + (size_t)N * 2;        // 128
  int* row_ptr = (int*)(stats + 128);        // N+1
  int* cursor  = row_ptr + (N + 1);          // N
  int* colbuf  = cursor + N;                 // E
  int* bsum    = colbuf + E;                 // 256
  int* boff    = bsum + 256;                 // 256

  const int nb = (N + 511) / 512;

  // ---- CSR build
  hipMemsetAsync(cursor, 0, sizeof(int) * (size_t)N, stream);
  hist_kernel<<<(E + 255) / 256, 256, 0, stream>>>(dstp, cursor, E);
  scan_phase1<<<nb, 256, 0, stream>>>(cursor, bsum, N);
  scan_phase2<<<1, 256, 0, stream>>>(bsum, boff, row_ptr + N, nb);
  scan_phase3<<<nb, 256, 0, stream>>>(cursor, boff, row_ptr, N);
  copy_kernel<<<(N + 255) / 256, 256, 0, stream>>>(row_ptr, cursor, N);
  scatter_kernel<<<(E + 255) / 256, 256, 0, stream>>>(srcp, dstp, cursor, colbuf, E);

  const int tiles = (N + 63) / 64;

  // ---- 3 GAT layers
  const float* in = x;
  for (int l = 0; l < 3; l++) {
    if (l == 0)
      gat_project_tiled<16><<<tiles, 256, 0, stream>>>(in, W[l], AS[l], AD[l],
                                                       hbuf, as_, ad_, N);
    else
      gat_project_tiled<64><<<tiles, 256, 0, stream>>>(in, W[l], AS[l], AD[l],
                                                       hbuf, as_, ad_, N);
    gat_aggregate<<<(N + 3) / 4, 256, 0, stream>>>(hbuf, as_, ad_, row_ptr, colbuf, B[l], bufB, N);
    hipMemsetAsync(stats, 0, sizeof(float) * 128, stream);
    bn_stats<<<1024, 256, 0, stream>>>(bufB, stats, N);
    bn_apply<<<(N * 64 + 255) / 256, 256, 0, stream>>>(bufB, stats, G[l], BE[l], bufA, N);
    in = bufA;
  }

  // ---- MLP head -> (logits, value)
  mlp_head_tiled<<<tiles, 256, 0, stream>>>(bufA, x, mW1, mb1, mW2, mb2,
                                            pW, pb, vW, vb, (float*)d_out, N);
}

// Round 6
// 728.832 us; speedup vs baseline: 1.8300x; 1.0618x over previous
//
#include <hip/hip_runtime.h>
#include <hip/hip_fp16.h>

// N=100000 nodes, E=1000000 edges, D_IN=16, H=2, C=64.
// 3x (GAT -> BN -> ReLU), then MLP head -> (logits, value) concat in d_out.
// hbuf stored fp16 (half2 pair-per-lane layout) to halve the edge-gather bytes.

__device__ __forceinline__ float leaky(float x) { return x > 0.f ? x : 0.2f * x; }

// ---------------- CSR build (dst-sorted; self-loops implicit) ----------------
__global__ void hist_kernel(const int* __restrict__ dst, int* __restrict__ deg, int E) {
  int e = blockIdx.x * blockDim.x + threadIdx.x;
  if (e < E) atomicAdd(&deg[dst[e]], 1);
}

__global__ void scan_phase1(const int* __restrict__ deg, int* __restrict__ bsum, int n) {
  __shared__ int red[256];
  int t = threadIdx.x;
  int i0 = blockIdx.x * 512 + t * 2;
  int d0 = (i0 < n) ? deg[i0] : 0;
  int d1 = (i0 + 1 < n) ? deg[i0 + 1] : 0;
  red[t] = d0 + d1;
  __syncthreads();
  for (int off = 128; off; off >>= 1) {
    if (t < off) red[t] += red[t + off];
    __syncthreads();
  }
  if (t == 0) bsum[blockIdx.x] = red[0];
}

__global__ void scan_phase2(const int* __restrict__ bsum, int* __restrict__ boff,
                            int* __restrict__ row_ptr_last, int nb) {
  __shared__ int temp[256];
  int t = threadIdx.x;
  int v = (t < nb) ? bsum[t] : 0;
  temp[t] = v;
  __syncthreads();
  for (int off = 1; off < 256; off <<= 1) {
    int add = (t >= off) ? temp[t - off] : 0;
    __syncthreads();
    temp[t] += add;
    __syncthreads();
  }
  if (t < nb) boff[t] = temp[t] - v;           // exclusive
  if (t == nb - 1) *row_ptr_last = temp[t];    // grand total -> row_ptr[N]
}

__global__ void scan_phase3(const int* __restrict__ deg, const int* __restrict__ boff,
                            int* __restrict__ row_ptr, int n) {
  __shared__ int temp[256];
  int t = threadIdx.x;
  int i0 = blockIdx.x * 512 + t * 2;
  int d0 = (i0 < n) ? deg[i0] : 0;
  int d1 = (i0 + 1 < n) ? deg[i0 + 1] : 0;
  int pair = d0 + d1;
  temp[t] = pair;
  __syncthreads();
  for (int off = 1; off < 256; off <<= 1) {
    int add = (t >= off) ? temp[t - off] : 0;
    __syncthreads();
    temp[t] += add;
    __syncthreads();
  }
  int excl = boff[blockIdx.x] + temp[t] - pair;
  if (i0 < n) row_ptr[i0] = excl;
  if (i0 + 1 < n) row_ptr[i0 + 1] = excl + d0;
}

__global__ void copy_kernel(const int* __restrict__ a, int* __restrict__ b, int n) {
  int i = blockIdx.x * blockDim.x + threadIdx.x;
  if (i < n) b[i] = a[i];
}

__global__ void scatter_kernel(const int* __restrict__ src, const int* __restrict__ dst,
                               int* __restrict__ cursor, int* __restrict__ col, int E) {
  int e = blockIdx.x * blockDim.x + threadIdx.x;
  if (e < E) {
    int d = dst[e];
    int pos = atomicAdd(&cursor[d], 1);
    col[pos] = src[e];
  }
}

// ---------------- GAT projection: LDS-tiled GEMM, 64 nodes x 128 cols -------
// h = act @ W; writes hbuf as half2 pairs: hb[node*64 + c/2] = (h[c], h[c+1]).
// a_s/a_d computed from f32 accumulators (full precision scores).
template <int K>
__global__ __launch_bounds__(256) void gat_project_tiled(
    const float* __restrict__ act, const float* __restrict__ W,
    const float* __restrict__ att_s, const float* __restrict__ att_d,
    __half2* __restrict__ hb, float* __restrict__ as_,
    float* __restrict__ ad_, int n) {
  constexpr int AST = K + 4;
  __shared__ float aS[64 * AST];
  __shared__ float wS[K * 128];
  __shared__ float attS[256];

  int t = threadIdx.x;
  int node0 = blockIdx.x * 64;
  int rows = min(64, n - node0);

  constexpr int AF4 = 64 * K / 4;
  for (int i = t; i < AF4; i += 256) {
    int r = i / (K / 4), kc = i % (K / 4);
    float4 v = make_float4(0.f, 0.f, 0.f, 0.f);
    if (r < rows) v = *(const float4*)&act[(size_t)(node0 + r) * K + kc * 4];
    *(float4*)&aS[r * AST + kc * 4] = v;
  }
  constexpr int WF4 = K * 32;
  for (int i = t; i < WF4; i += 256)
    *(float4*)&wS[i * 4] = *(const float4*)&W[i * 4];
  attS[t] = (t < 128) ? att_s[t] : att_d[t - 128];
  __syncthreads();

  int tc = t & 15, tr = t >> 4;
  int c0 = tc * 8, r0 = tr * 4;

  float acc[4][8] = {};
  for (int k = 0; k < K; k += 4) {
    float4 av[4];
    float4 wv[4][2];
#pragma unroll
    for (int i = 0; i < 4; i++) av[i] = *(const float4*)&aS[(r0 + i) * AST + k];
#pragma unroll
    for (int kk = 0; kk < 4; kk++) {
      wv[kk][0] = *(const float4*)&wS[(k + kk) * 128 + c0];
      wv[kk][1] = *(const float4*)&wS[(k + kk) * 128 + c0 + 4];
    }
#pragma unroll
    for (int i = 0; i < 4; i++) {
      const float* ai = (const float*)&av[i];
#pragma unroll
      for (int kk = 0; kk < 4; kk++) {
        const float* w0 = (const float*)&wv[kk][0];
        const float* w1 = (const float*)&wv[kk][1];
#pragma unroll
        for (int j = 0; j < 4; j++) {
          acc[i][j] = fmaf(ai[kk], w0[j], acc[i][j]);
          acc[i][4 + j] = fmaf(ai[kk], w1[j], acc[i][4 + j]);
        }
      }
    }
  }

#pragma unroll
  for (int i = 0; i < 4; i++) {
    int r = r0 + i;
    float psv = 0.f, pdv = 0.f;
#pragma unroll
    for (int j = 0; j < 8; j++) {
      psv = fmaf(acc[i][j], attS[c0 + j], psv);
      pdv = fmaf(acc[i][j], attS[128 + c0 + j], pdv);
    }
    psv += __shfl_xor(psv, 1); pdv += __shfl_xor(pdv, 1);
    psv += __shfl_xor(psv, 2); pdv += __shfl_xor(pdv, 2);
    psv += __shfl_xor(psv, 4); pdv += __shfl_xor(pdv, 4);
    if (r < rows) {
      size_t base = (size_t)(node0 + r) * 64 + (c0 >> 1);
      hb[base + 0] = __floats2half2_rn(acc[i][0], acc[i][1]);
      hb[base + 1] = __floats2half2_rn(acc[i][2], acc[i][3]);
      hb[base + 2] = __floats2half2_rn(acc[i][4], acc[i][5]);
      hb[base + 3] = __floats2half2_rn(acc[i][6], acc[i][7]);
      if (tc == 0 || tc == 8) {
        int head = tc >> 3;
        as_[(node0 + r) * 2 + head] = psv;
        ad_[(node0 + r) * 2 + head] = pdv;
      }
    }
  }
}

// ---------------- GAT aggregation: one wave per dst node ---------------------
// Lane l holds channels {2l, 2l+1}; lanes 0..31 = head 0, 32..63 = head 1.
// One half2 (4 B/lane) gather per edge = 256 B/wave.
__global__ __launch_bounds__(256) void gat_aggregate(
    const __half2* __restrict__ hb, const float* __restrict__ as_,
    const float* __restrict__ ad_, const int* __restrict__ row_ptr,
    const int* __restrict__ col, const float* __restrict__ bias,
    float* __restrict__ out, int n) {
  int wave = (int)((blockIdx.x * blockDim.x + threadIdx.x) >> 6);
  int lane = threadIdx.x & 63;
  if (wave >= n) return;
  int d = wave;
  int beg = row_ptr[d], end = row_ptr[d + 1];
  float ad0 = ad_[d * 2 + 0], ad1 = ad_[d * 2 + 1];
  int head = lane >> 5;

  float2 accA, accB = make_float2(0.f, 0.f);
  float den0a, den1a, den0b = 0.f, den1b = 0.f;
  {
    float ee0 = __expf(leaky(as_[d * 2 + 0] + ad0));
    float ee1 = __expf(leaky(as_[d * 2 + 1] + ad1));
    float2 hv = __half22float2(hb[(size_t)d * 64 + lane]);
    float ee = head ? ee1 : ee0;
    den0a = ee0; den1a = ee1;
    accA.x = ee * hv.x; accA.y = ee * hv.y;
  }
  int k = beg;
  for (; k + 1 < end; k += 2) {
    int sA = col[k], sB = col[k + 1];
    float eA0 = leaky(as_[sA * 2 + 0] + ad0);
    float eA1 = leaky(as_[sA * 2 + 1] + ad1);
    float eB0 = leaky(as_[sB * 2 + 0] + ad0);
    float eB1 = leaky(as_[sB * 2 + 1] + ad1);
    float2 hA = __half22float2(hb[(size_t)sA * 64 + lane]);
    float2 hB = __half22float2(hb[(size_t)sB * 64 + lane]);
    float eeA0 = __expf(eA0), eeA1 = __expf(eA1);
    float eeB0 = __expf(eB0), eeB1 = __expf(eB1);
    float eeA = head ? eeA1 : eeA0;
    float eeB = head ? eeB1 : eeB0;
    den0a += eeA0; den1a += eeA1;
    den0b += eeB0; den1b += eeB1;
    accA.x = fmaf(eeA, hA.x, accA.x);
    accA.y = fmaf(eeA, hA.y, accA.y);
    accB.x = fmaf(eeB, hB.x, accB.x);
    accB.y = fmaf(eeB, hB.y, accB.y);
  }
  for (; k < end; ++k) {
    int s = col[k];
    float e0 = leaky(as_[s * 2 + 0] + ad0);
    float e1 = leaky(as_[s * 2 + 1] + ad1);
    float2 hv = __half22float2(hb[(size_t)s * 64 + lane]);
    float ee0 = __expf(e0), ee1 = __expf(e1);
    float ee = head ? ee1 : ee0;
    den0a += ee0; den1a += ee1;
    accA.x = fmaf(ee, hv.x, accA.x);
    accA.y = fmaf(ee, hv.y, accA.y);
  }
  float ax = accA.x + accB.x, ay = accA.y + accB.y;
  float den0 = den0a + den0b, den1 = den1a + den1b;
  // lanes 0..31 (head 0) pull head-1 partials from partner lane l+32
  float px = __shfl(ax, (lane + 32) & 63);
  float py = __shfl(ay, (lane + 32) & 63);
  if (lane < 32) {
    float r0 = 1.f / (den0 + 1e-16f), r1 = 1.f / (den1 + 1e-16f);
    float2 b = *(const float2*)&bias[lane * 2];
    float2 o;
    o.x = 0.5f * (ax * r0 + px * r1) + b.x;
    o.y = 0.5f * (ay * r0 + py * r1) + b.y;
    *(float2*)&out[(size_t)d * 64 + lane * 2] = o;
  }
}

// ---------------- BatchNorm ----------------
__global__ void bn_stats(const float* __restrict__ h, float* __restrict__ stats, int n) {
  __shared__ float ssum[64], ssq[64];
  int t = threadIdx.x;
  if (t < 64) { ssum[t] = 0.f; ssq[t] = 0.f; }
  __syncthreads();
  int c = t & 63;
  float lsum = 0.f, lsq = 0.f;
  size_t total = (size_t)n * 64;
  for (size_t i = (size_t)blockIdx.x * blockDim.x + t; i < total;
       i += (size_t)gridDim.x * blockDim.x) {
    float v = h[i];
    lsum += v;
    lsq = fmaf(v, v, lsq);
  }
  atomicAdd(&ssum[c], lsum);
  atomicAdd(&ssq[c], lsq);
  __syncthreads();
  if (t < 64) {
    atomicAdd(&stats[t], ssum[t]);
    atomicAdd(&stats[64 + t], ssq[t]);
  }
}

__global__ void bn_apply(const float* __restrict__ hin, const float* __restrict__ stats,
                         const float* __restrict__ g, const float* __restrict__ be,
                         float* __restrict__ out, int n) {
  size_t i = (size_t)blockIdx.x * blockDim.x + threadIdx.x;
  if (i >= (size_t)n * 64) return;
  int c = (int)(i & 63);
  float inv_n = 1.0f / (float)n;
  float mean = stats[c] * inv_n;
  float var = stats[64 + c] * inv_n - mean * mean;
  float sc = rsqrtf(var + 1e-5f) * g[c];
  float v = (hin[i] - mean) * sc + be[c];
  out[i] = v > 0.f ? v : 0.f;
}

// ---------------- MLP head: fused tiled GEMM (64 nodes / block) --------------
__global__ __launch_bounds__(256) void mlp_head_tiled(
    const float* __restrict__ h3, const float* __restrict__ x,
    const float* __restrict__ mW1, const float* __restrict__ mb1,
    const float* __restrict__ mW2, const float* __restrict__ mb2,
    const float* __restrict__ pW, const float* __restrict__ pb,
    const float* __restrict__ vW, const float* __restrict__ vb,
    float* __restrict__ out, int n) {
  __shared__ float lds[13632];
  float* a1  = lds;           // 64*68 = 4352
  float* ctx = lds + 4352;    // 64*8  = 512
  float* a2  = lds + 4864;    // 64*68 = 4352
  float* w1  = lds + 9216;    // 69*64 = 4416
  float* w2  = lds;           // aliases a1 (dead after GEMM1)

  int t = threadIdx.x;
  int node0 = blockIdx.x * 64;
  int rows = min(64, n - node0);

#pragma unroll
  for (int i = 0; i < 4; i++) {
    int flat = t + i * 256;
    int r = flat >> 4, kc = flat & 15;
    float4 v = make_float4(0.f, 0.f, 0.f, 0.f);
    if (r < rows) v = *(const float4*)&h3[(size_t)(node0 + r) * 64 + kc * 4];
    *(float4*)&a1[r * 68 + kc * 4] = v;
  }
  for (int i = t; i < 320; i += 256) {
    int r = i / 5, j = i % 5;
    ctx[r * 8 + j] = (r < rows) ? x[(size_t)(node0 + r) * 16 + 9 + j] : 0.f;
  }
#pragma unroll
  for (int i = 0; i < 5; i++) {
    int flat = t + i * 256;
    if (flat < 1104) *(float4*)&w1[flat * 4] = *(const float4*)&mW1[flat * 4];
  }
  __syncthreads();

  int tc = t & 15, tr = t >> 4;
  int c0 = tc * 4, r0 = tr * 4;

  float acc[4][4] = {};
  for (int k = 0; k < 64; k += 4) {
    float4 av[4], wv[4];
#pragma unroll
    for (int i = 0; i < 4; i++) av[i] = *(const float4*)&a1[(r0 + i) * 68 + k];
#pragma unroll
    for (int j = 0; j < 4; j++) wv[j] = *(const float4*)&w1[(k + j) * 64 + c0];
#pragma unroll
    for (int i = 0; i < 4; i++) {
      const float* ai = (const float*)&av[i];
#pragma unroll
      for (int kk = 0; kk < 4; kk++) {
        const float* wr = (const float*)&wv[kk];
        acc[i][0] = fmaf(ai[kk], wr[0], acc[i][0]);
        acc[i][1] = fmaf(ai[kk], wr[1], acc[i][1]);
        acc[i][2] = fmaf(ai[kk], wr[2], acc[i][2]);
        acc[i][3] = fmaf(ai[kk], wr[3], acc[i][3]);
      }
    }
  }
#pragma unroll
  for (int k = 64; k < 69; k++) {
    float4 wv = *(const float4*)&w1[k * 64 + c0];
    const float* wr = (const float*)&wv;
#pragma unroll
    for (int i = 0; i < 4; i++) {
      float a = ctx[(r0 + i) * 8 + (k - 64)];
      acc[i][0] = fmaf(a, wr[0], acc[i][0]);
      acc[i][1] = fmaf(a, wr[1], acc[i][1]);
      acc[i][2] = fmaf(a, wr[2], acc[i][2]);
      acc[i][3] = fmaf(a, wr[3], acc[i][3]);
    }
  }
  float b1v0 = mb1[c0], b1v1 = mb1[c0 + 1], b1v2 = mb1[c0 + 2], b1v3 = mb1[c0 + 3];
#pragma unroll
  for (int i = 0; i < 4; i++) {
    float4 t1;
    t1.x = fmaxf(acc[i][0] + b1v0, 0.f);
    t1.y = fmaxf(acc[i][1] + b1v1, 0.f);
    t1.z = fmaxf(acc[i][2] + b1v2, 0.f);
    t1.w = fmaxf(acc[i][3] + b1v3, 0.f);
    *(float4*)&a2[(r0 + i) * 68 + c0] = t1;
  }
  __syncthreads();

#pragma unroll
  for (int i = 0; i < 4; i++) {
    int flat = t + i * 256;
    *(float4*)&w2[flat * 4] = *(const float4*)&mW2[flat * 4];
  }
  __syncthreads();

  float acc2[4][4] = {};
  for (int k = 0; k < 64; k += 4) {
    float4 av[4], wv[4];
#pragma unroll
    for (int i = 0; i < 4; i++) av[i] = *(const float4*)&a2[(r0 + i) * 68 + k];
#pragma unroll
    for (int j = 0; j < 4; j++) wv[j] = *(const float4*)&w2[(k + j) * 64 + c0];
#pragma unroll
    for (int i = 0; i < 4; i++) {
      const float* ai = (const float*)&av[i];
#pragma unroll
      for (int kk = 0; kk < 4; kk++) {
        const float* wr = (const float*)&wv[kk];
        acc2[i][0] = fmaf(ai[kk], wr[0], acc2[i][0]);
        acc2[i][1] = fmaf(ai[kk], wr[1], acc2[i][1]);
        acc2[i][2] = fmaf(ai[kk], wr[2], acc2[i][2]);
        acc2[i][3] = fmaf(ai[kk], wr[3], acc2[i][3]);
      }
    }
  }

  float b2v[4], pwv[4], vwv[4];
#pragma unroll
  for (int j = 0; j < 4; j++) {
    b2v[j] = mb2[c0 + j];
    pwv[j] = pW[c0 + j];
    vwv[j] = vW[c0 + j];
  }
  float p[4], v[4];
#pragma unroll
  for (int i = 0; i < 4; i++) {
    float ps = 0.f, vs = 0.f;
#pragma unroll
    for (int j = 0; j < 4; j++) {
      float u = acc2[i][j] + b2v[j];
      ps = fmaf(u, pwv[j], ps);
      vs = fmaf(u, vwv[j], vs);
    }
    p[i] = ps; v[i] = vs;
  }
#pragma unroll
  for (int off = 1; off < 16; off <<= 1) {
#pragma unroll
    for (int i = 0; i < 4; i++) {
      p[i] += __shfl_xor(p[i], off);
      v[i] += __shfl_xor(v[i], off);
    }
  }
  if (tc == 0) {
    float pbs = pb[0], vbs = vb[0];
#pragma unroll
    for (int i = 0; i < 4; i++) {
      int r = r0 + i;
      if (r < rows) {
        out[node0 + r] = p[i] + pbs;
        out[n + node0 + r] = v[i] + vbs;
      }
    }
  }
}

extern "C" void kernel_launch(void* const* d_in, const int* in_sizes, int n_in,
                              void* d_out, int out_size, void* d_ws, size_t ws_size,
                              hipStream_t stream) {
  const float* x = (const float*)d_in[0];
  const int* ei = (const int*)d_in[1];
  const float* W[3]  = {(const float*)d_in[2],  (const float*)d_in[8],  (const float*)d_in[14]};
  const float* AS[3] = {(const float*)d_in[3],  (const float*)d_in[9],  (const float*)d_in[15]};
  const float* AD[3] = {(const float*)d_in[4],  (const float*)d_in[10], (const float*)d_in[16]};
  const float* B[3]  = {(const float*)d_in[5],  (const float*)d_in[11], (const float*)d_in[17]};
  const float* G[3]  = {(const float*)d_in[6],  (const float*)d_in[12], (const float*)d_in[18]};
  const float* BE[3] = {(const float*)d_in[7],  (const float*)d_in[13], (const float*)d_in[19]};
  const float* mW1 = (const float*)d_in[20];
  const float* mb1 = (const float*)d_in[21];
  const float* mW2 = (const float*)d_in[22];
  const float* mb2 = (const float*)d_in[23];
  const float* pW  = (const float*)d_in[24];
  const float* pb  = (const float*)d_in[25];
  const float* vW  = (const float*)d_in[26];
  const float* vb  = (const float*)d_in[27];

  const int N = in_sizes[0] / 16;
  const int E = in_sizes[1] / 2;
  const int* srcp = ei;
  const int* dstp = ei + E;

  float* bufA  = (float*)d_ws;               // N*64  activations (layer in/out)
  float* bufB  = bufA + (size_t)N * 64;      // N*64  pre-BN aggregation output
  float* hbuf  = bufB + (size_t)N * 64;      // N*64 half2 (region sized N*128 f32)
  float* as_   = hbuf + (size_t)N * 128;     // N*2
  float* ad_   = as_ + (size_t)N * 2;        // N*2
  float* stats = ad_ + (size_t)N * 2;        // 128
  int* row_ptr = (int*)(stats + 128);        // N+1
  int* cursor  = row_ptr + (N + 1);          // N
  int* colbuf  = cursor + N;                 // E
  int* bsum    = colbuf + E;                 // 256
  int* boff    = bsum + 256;                 // 256
  __half2* hb  = (__half2*)hbuf;

  const int nb = (N + 511) / 512;

  // ---- CSR build
  hipMemsetAsync(cursor, 0, sizeof(int) * (size_t)N, stream);
  hist_kernel<<<(E + 255) / 256, 256, 0, stream>>>(dstp, cursor, E);
  scan_phase1<<<nb, 256, 0, stream>>>(cursor, bsum, N);
  scan_phase2<<<1, 256, 0, stream>>>(bsum, boff, row_ptr + N, nb);
  scan_phase3<<<nb, 256, 0, stream>>>(cursor, boff, row_ptr, N);
  copy_kernel<<<(N + 255) / 256, 256, 0, stream>>>(row_ptr, cursor, N);
  scatter_kernel<<<(E + 255) / 256, 256, 0, stream>>>(srcp, dstp, cursor, colbuf, E);

  const int tiles = (N + 63) / 64;

  // ---- 3 GAT layers
  const float* in = x;
  for (int l = 0; l < 3; l++) {
    if (l == 0)
      gat_project_tiled<16><<<tiles, 256, 0, stream>>>(in, W[l], AS[l], AD[l],
                                                       hb, as_, ad_, N);
    else
      gat_project_tiled<64><<<tiles, 256, 0, stream>>>(in, W[l], AS[l], AD[l],
                                                       hb, as_, ad_, N);
    gat_aggregate<<<(N + 3) / 4, 256, 0, stream>>>(hb, as_, ad_, row_ptr, colbuf, B[l], bufB, N);
    hipMemsetAsync(stats, 0, sizeof(float) * 128, stream);
    bn_stats<<<1024, 256, 0, stream>>>(bufB, stats, N);
    bn_apply<<<(N * 64 + 255) / 256, 256, 0, stream>>>(bufB, stats, G[l], BE[l], bufA, N);
    in = bufA;
  }

  // ---- MLP head -> (logits, value)
  mlp_head_tiled<<<tiles, 256, 0, stream>>>(bufA, x, mW1, mb1, mW2, mb2,
                                            pW, pb, vW, vb, (float*)d_out, N);
}